// Round 9
// baseline (901.090 us; speedup 1.0000x reference)
//
#include <hip/hip_runtime.h>
#include <stdint.h>

typedef unsigned short u16;
typedef unsigned int   u32;

#define NNODES 10000
#define NEDGES 20000
#define ETOT   30000
#define NHEADS 12
#define CDIM   768
#define FDIM   768
#define KDIM   9216    // h*768+k flattened head-input dim (GEMM K)
#define NGRAPH 64
#define MPAD   10240   // y padded rows; pad rows zeroed per plane, outputs guarded
#define NEG_SLOPE 0.2f
#define DMAX   32      // max in-degree incl. self-loop; max of 10000 Poisson(2) ~ 14
#define NPLANE 144     // KDIM/64 K-planes in the tiled y/Bt2 layouts

typedef __attribute__((ext_vector_type(8))) short short8;
typedef __attribute__((ext_vector_type(4))) float f32x4;

__device__ __forceinline__ u16 f32_bf16(float f) {
  u32 u = __float_as_uint(f);
  u = (u + 0x7FFFu + ((u >> 16) & 1u)) >> 16;
  return (u16)u;
}
__device__ __forceinline__ float bf16_f32(u16 v) {
  return __uint_as_float(((u32)v) << 16);
}

// ---------------- CSR build ----------------
__global__ void k_count(const int* __restrict__ dste, int* __restrict__ counts) {
  int e = blockIdx.x * blockDim.x + threadIdx.x;
  if (e >= ETOT) return;
  int dst;
  if (e < NEDGES) dst = dste[e]; else dst = e - NEDGES;
  atomicAdd(&counts[dst], 1);
}

__global__ void k_scan(const int* __restrict__ counts, int* __restrict__ offs) {
  __shared__ int part[256];
  int t = threadIdx.x;
  const int chunk = 40;
  int beg = t * chunk;
  int end = beg + chunk; if (end > NNODES) end = NNODES;
  int s = 0;
  for (int i = beg; i < end && i < NNODES; i++) s += counts[i];
  part[t] = s;
  __syncthreads();
  for (int d = 1; d < 256; d <<= 1) {
    int v = (t >= d) ? part[t - d] : 0;
    __syncthreads();
    part[t] += v;
    __syncthreads();
  }
  int base = (t == 0) ? 0 : part[t - 1];
  for (int i = beg; i < end && i < NNODES; i++) { offs[i] = base; base += counts[i]; }
  if (t == 255) offs[NNODES] = base;
}

__global__ void k_seed(const int* __restrict__ offs, int* __restrict__ cursor) {
  int n = blockIdx.x * blockDim.x + threadIdx.x;
  if (n < NNODES) cursor[n] = offs[n];
}

__global__ void k_scatter(const int* __restrict__ dste, int* __restrict__ cursor,
                          int* __restrict__ elist) {
  int e = blockIdx.x * blockDim.x + threadIdx.x;
  if (e >= ETOT) return;
  int dst;
  if (e < NEDGES) dst = dste[e]; else dst = e - NEDGES;
  int pos = atomicAdd(&cursor[dst], 1);
  elist[pos] = e;
}

// ------- Ut[o*768+k] = sum_c W[k, h*768+c] * a[h, c] ; 4 waves x 6 o's per block -------
__global__ void k_U(const float* __restrict__ W, const float* __restrict__ a_src,
                    const float* __restrict__ a_dst, float* __restrict__ Ut) {
  int k = blockIdx.x;
  int t = threadIdx.x, w = t >> 6, l = t & 63;
  const float* Wrow = W + (size_t)k * KDIM;
#pragma unroll
  for (int q = 0; q < 6; q++) {
    int o = w * 6 + q;
    int h = (o < 12) ? o : o - 12;
    const float* av = (o < 12) ? (a_src + h * CDIM) : (a_dst + h * CDIM);
    const float* wr = Wrow + h * CDIM;
    float p = 0.f;
    for (int c = l; c < CDIM; c += 64) p += wr[c] * av[c];
#pragma unroll
    for (int d = 32; d > 0; d >>= 1) p += __shfl_down(p, d, 64);
    if (l == 0) Ut[o * FDIM + k] = p;
  }
}

// ---- sd: Ut staged in LDS once per block; 20 nodes/block. ----
__global__ void k_sd(const float* __restrict__ xin, const float* __restrict__ Ut,
                     float* __restrict__ sd) {
  __shared__ float UtS[24 * FDIM];   // 73728 B
  int t = threadIdx.x, w = t >> 6, l = t & 63;
  const float4* U4 = (const float4*)Ut;
  float4* S4 = (float4*)UtS;
  for (int i = t; i < 24 * FDIM / 4; i += 256) S4[i] = U4[i];
  __syncthreads();
#pragma unroll
  for (int rep = 0; rep < 5; rep++) {
    int n = blockIdx.x * 20 + w * 5 + rep;
    if (n >= NNODES) continue;
    const float* xr = xin + (size_t)n * FDIM;
    float4 x0 = *(const float4*)(xr + 4 * l);
    float4 x1 = *(const float4*)(xr + 4 * l + 256);
    float4 x2 = *(const float4*)(xr + 4 * l + 512);
#pragma unroll
    for (int o = 0; o < 24; o++) {
      const float4* up = (const float4*)(UtS + o * FDIM + 4 * l);
      float4 u0 = up[0];
      float4 u1 = up[64];
      float4 u2 = up[128];
      float a = x0.x * u0.x + x0.y * u0.y + x0.z * u0.z + x0.w * u0.w
              + x1.x * u1.x + x1.y * u1.y + x1.z * u1.z + x1.w * u1.w
              + x2.x * u2.x + x2.y * u2.y + x2.z * u2.z + x2.w * u2.w;
#pragma unroll
      for (int d = 32; d > 0; d >>= 1) a += __shfl_xor(a, d, 64);
      if (l == 0) sd[n * 24 + o] = a;
    }
  }
}

// -------- Bt2 K-TILED: Bt2[kt][c][64] = bf16(W[k, h*768+c]), kt = (h*768+k)/64.
//          Dense 64B-contiguous rows so GEMM staging loads are unscattered. --------
__global__ void k_trans2(const float* __restrict__ W, u16* __restrict__ Bt2) {
  int kb = blockIdx.x * 32, jt = blockIdx.y * 32;   // kb: W-row tile; jt = h*768+c tile
  int tx = threadIdx.x, ty = threadIdx.y;  // 32, 8
  __shared__ float tile[32][33];
  int h0 = jt / 768, c0 = jt - h0 * 768;
  int plane = (h0 * 768 + kb) >> 6;        // kb%64 in {0,32}: tx<32 never carries
#pragma unroll
  for (int r = 0; r < 4; r++)
    tile[ty + 8 * r][tx] = W[(size_t)(kb + ty + 8 * r) * KDIM + jt + tx];
  __syncthreads();
#pragma unroll
  for (int r = 0; r < 4; r++)
    Bt2[(size_t)plane * (768 * 64) + (size_t)(c0 + ty + 8 * r) * 64 + ((kb + tx) & 63)]
        = f32_bf16(tile[tx][ty + 8 * r]);
}

// ---- k_zpad: zero pad rows [NNODES,MPAD) of every y plane (run once; k_agg
//      only writes n<NNODES so pads stay zero across layers). ----
__global__ void k_zpad(u16* __restrict__ y) {
  int idx = blockIdx.x * 256 + threadIdx.x;   // 144 planes * 240 rows * 64 / 8 = 276480
  if (idx >= NPLANE * (MPAD - NNODES) * 8) return;
  int e = idx * 8;
  int plane = e / ((MPAD - NNODES) * 64);
  int rem = e - plane * ((MPAD - NNODES) * 64);
  u16* p = y + (size_t)plane * (MPAD * 64) + (size_t)NNODES * 64 + rem;
  *(short8*)p = (short8){0, 0, 0, 0, 0, 0, 0, 0};
}

// ---- k_agg: softmax + aggregation in input space (r7: ~86 us/layer faster than
//      Hbig-gather). Output now K-TILED: y[kt][n][64], kt = (h*768+pass*256+4l)/64. ----
__global__ void k_agg(const float* __restrict__ xin, const int* __restrict__ ei,
                      const int* __restrict__ offs, const int* __restrict__ elist,
                      const float* __restrict__ sd, u16* __restrict__ y) {
  int t = threadIdx.x, w = t >> 6, l = t & 63;
  int n = blockIdx.x * 4 + w;
  __shared__ int   srcsS[4][DMAX];
  __shared__ float alphS[4][NHEADS * DMAX];
  if (n >= NNODES) return;          // no block barriers below
  int* srcs = srcsS[w];
  float* alph = alphS[w];
  int beg = offs[n];
  int deg = offs[n + 1] - beg;
  if (deg > DMAX) deg = DMAX;
  if (l < deg) {
    int e = elist[beg + l];
    srcs[l] = (e < NEDGES) ? ei[e] : e - NEDGES;
  }
  __builtin_amdgcn_wave_barrier();
  for (int p = l; p < deg * NHEADS; p += 64) {
    int i = p / NHEADS, h = p - i * NHEADS;
    float v = sd[srcs[i] * 24 + h] + sd[n * 24 + 12 + h];
    v = (v > 0.f) ? v : NEG_SLOPE * v;
    alph[h * DMAX + i] = v;
  }
  __builtin_amdgcn_wave_barrier();
  if (l < NHEADS) {
    float m = -1e30f;
    for (int i = 0; i < deg; i++) m = fmaxf(m, alph[l * DMAX + i]);
    float s = 0.f;
    for (int i = 0; i < deg; i++) {
      float ex = expf(alph[l * DMAX + i] - m);
      alph[l * DMAX + i] = ex;
      s += ex;
    }
    float inv = 1.f / (s + 1e-16f);
    for (int i = 0; i < deg; i++) alph[l * DMAX + i] *= inv;
  }
  __builtin_amdgcn_wave_barrier();
  int lg = l >> 4, lo16 = l & 15;
#pragma unroll
  for (int pass = 0; pass < 3; pass++) {
    float4 acc12[NHEADS];
#pragma unroll
    for (int h = 0; h < NHEADS; h++) acc12[h] = make_float4(0.f, 0.f, 0.f, 0.f);
    for (int i = 0; i < deg; i++) {
      float4 xs = *(const float4*)(xin + (size_t)srcs[i] * FDIM + pass * 256 + 4 * l);
#pragma unroll
      for (int h = 0; h < NHEADS; h++) {
        float a = alph[h * DMAX + i];
        acc12[h].x += a * xs.x;
        acc12[h].y += a * xs.y;
        acc12[h].z += a * xs.z;
        acc12[h].w += a * xs.w;
      }
    }
#pragma unroll
    for (int h = 0; h < NHEADS; h++) {
      ushort4 pv;
      pv.x = f32_bf16(acc12[h].x);
      pv.y = f32_bf16(acc12[h].y);
      pv.z = f32_bf16(acc12[h].z);
      pv.w = f32_bf16(acc12[h].w);
      int plane = h * 12 + pass * 4 + lg;       // (h*768+pass*256+4l)/64
      *(ushort4*)(y + (size_t)plane * (MPAD * 64) + (size_t)n * 64 + 4 * lo16) = pv;
    }
  }
}

// ============================================================================
// GEMM2 (2 BLOCKS/CU): partial[n,c] = sum_kk y[n,kk]*Bt2[c,kk], split-K=2.
// r8 POST-MORTEM: per-tile cost ~6500 cyc is invariant across 3 structures at
// 1 block/CU — phase barriers serialize {ds_read, MFMA, stage} with nothing
// else resident (r0's naive 2-phase matched r6's 8-phase BECAUSE it had
// 1.6 blocks/CU; m114 cross-block overlap is the missing mechanism).
// This version: tile 256x128, wave 64x64 (acc 64 + frags 32 regs), BK=32,
// LDS 48 KiB, launch_bounds(512,4) -> 2 blocks/CU by VGPR (<=128/wave).
// Grid 40 x 6 x 2(ks) = 480 ~ 1.9 blocks/CU, single round.
// Operands K-TILED (y[kt][MPAD][64], Bt2[kt][768][64]) so every staging load
// is 128B-stride dense (r8's 18KB-row scatter removed).
// Schedule (r6 ledger rescaled, audited): per tile s (buf P=s&1, K0=K0b+s):
//   p0: ldA(alo,m01)+ldB(blo,n01) | bar | mm | bar
//   p1: ldB(bhi,n23) | issue A_h1(s+1)->P^1 | bar | mm | bar
//   p2: ldA(ahi,m23) | issue B(s+2)->P  [B buf free after p1] | bar | mm | bar
//   p3: issue A_h0(s+2)->P [A buf free after p2] | bar | mm | vmcnt | bar
// Issues/tile = 3; steady outstanding at tile end = {B(s+2),A0(s+2)} ->
// vmcnt(2); tail s=NIT-2 -> vmcnt(0), s=NIT-1 no waits. Prologue: B(0),A0(0),
// A1(0),B(1),A0(1) then vmcnt(2). Overwrite-safety: each same-buf issue comes
// after the barrier that follows the last MFMA consuming that region (MFMA's
// lgkmcnt guarantees the ds_reads returned; barrier orders cross-wave).
// T2 swizzle for 64B rows: slot = lg ^ (lr&3), source pre-swizzle (t&3)^(rb&3).
// ============================================================================
#define GLL16(G, L) __builtin_amdgcn_global_load_lds( \
  (const __attribute__((address_space(1))) void*)(G), \
  (__attribute__((address_space(3))) void*)(L), 16, 0, 0)

__global__ __launch_bounds__(512, 4) void k_gemm2(const u16* __restrict__ A,
    const u16* __restrict__ B, float* __restrict__ C0, float* __restrict__ C1) {
  __shared__ __align__(16) u16 As[2][256 * 32];   // 16 KB per buffer
  __shared__ __align__(16) u16 Bs[2][128 * 32];   // 8 KB per buffer; total 48 KiB
  int t = threadIdx.x;
  int w = t >> 6, l = t & 63;
  int bid = blockIdx.x;                 // 480
  int xcd = bid & 7, j = bid >> 3;      // [0,60)
  int p = j / 12, rem = j - p * 12;
  int ks = rem / 6, cx = rem - ks * 6;  // 6 cx blocks share one A panel (L2)
  int row0 = (xcd * 5 + p) * 256, col0 = cx * 128;
  int K0b = ks * NPLANE;                // K position in 32-col units: ks*144
  int wr = w >> 1, wc = w & 1;          // wave grid 4 (M) x 2 (N), wave 64x64
  int lr = l & 15, lg = l >> 4;
  int koff = lg * 16;                   // byte offset of k-octet in 64B LDS row
  int swzr = (lr & 3) << 4;             // T2 read-side XOR (row&3 == lr&3)
  int rb = t >> 2;                      // 0..127 staged rows per issue
  int csw = ((t & 3) ^ (rb & 3)) * 8;   // pre-swizzled source chunk (u16)

  f32x4 acc[4][4] = {};
  short8 alo[2], ahi[2], blo[2], bhi[2];

  auto stA = [&](int buf, int h, int K0) {   // A half h: 128 rows, 8 KB, 1 issue
    int kt2 = K0 >> 1, hf = (K0 & 1) * 32;
    const u16* g = A + (size_t)kt2 * (MPAD * 64)
                     + (size_t)(row0 + h * 128 + rb) * 64 + hf + csw;
    GLL16(g, (u16*)&As[buf][0] + h * 4096 + (w << 9));
  };
  auto stB = [&](int buf, int K0) {          // B: 128 rows, 8 KB, 1 issue
    int kt2 = K0 >> 1, hf = (K0 & 1) * 32;
    const u16* g = B + (size_t)kt2 * (768 * 64)
                     + (size_t)(col0 + rb) * 64 + hf + csw;
    GLL16(g, (u16*)&Bs[buf][0] + (w << 9));
  };
  auto ldA = [&](int buf, short8* d, int mo) {
#pragma unroll
    for (int m = 0; m < 2; m++) {
      int row = wr * 64 + (mo + m) * 16 + lr;
      d[m] = *(const short8*)((const char*)&As[buf][0] + row * 64 + (koff ^ swzr));
    }
  };
  auto ldB = [&](int buf, short8* d, int no) {
#pragma unroll
    for (int n = 0; n < 2; n++) {
      int row = wc * 64 + (no + n) * 16 + lr;
      d[n] = *(const short8*)((const char*)&Bs[buf][0] + row * 64 + (koff ^ swzr));
    }
  };
  auto mm4 = [&](short8* aa, short8* bb, int mo, int no) {   // 4 MFMA, T5-wrapped
    __builtin_amdgcn_s_setprio(1);
#pragma unroll
    for (int m = 0; m < 2; m++)
#pragma unroll
      for (int n = 0; n < 2; n++)
        acc[mo + m][no + n] = __builtin_amdgcn_mfma_f32_16x16x32_bf16(
            aa[m], bb[n], acc[mo + m][no + n], 0, 0, 0);
    __builtin_amdgcn_s_setprio(0);
  };

  // prologue: tile0 {B,A0,A1}, tile1 {B,A0} — newest 2 stay in flight
  stB(0, K0b); stA(0, 0, K0b); stA(0, 1, K0b);
  stB(1, K0b + 1); stA(1, 0, K0b + 1);
  asm volatile("s_waitcnt vmcnt(2)" ::: "memory");
  __builtin_amdgcn_s_barrier();

  const int NIT = NPLANE;   // 144 K-tiles of 32
  for (int s = 0; s < NIT; s++) {
    int P = s & 1;
    int K0 = K0b + s;
    // p0: (m01,n01)
    ldA(P, alo, 0); ldB(P, blo, 0);
    __builtin_amdgcn_s_barrier();
    mm4(alo, blo, 0, 0);
    __builtin_amdgcn_s_barrier();
    // p1: (m01,n23)
    ldB(P, bhi, 2);
    if (s + 1 < NIT) stA(P ^ 1, 1, K0 + 1);
    __builtin_amdgcn_s_barrier();
    mm4(alo, bhi, 0, 2);
    __builtin_amdgcn_s_barrier();
    // p2: (m23,n23)
    ldA(P, ahi, 2);
    if (s + 2 < NIT) stB(P, K0 + 2);
    __builtin_amdgcn_s_barrier();
    mm4(ahi, bhi, 2, 2);
    __builtin_amdgcn_s_barrier();
    // p3: (m23,n01)
    if (s + 2 < NIT) stA(P, 0, K0 + 2);
    __builtin_amdgcn_s_barrier();
    mm4(ahi, blo, 2, 0);
    if (s < NIT - 1) {
      if (s <= NIT - 3) asm volatile("s_waitcnt vmcnt(2)" ::: "memory");
      else              asm volatile("s_waitcnt vmcnt(0)" ::: "memory");
    }
    __builtin_amdgcn_s_barrier();
  }

  // epilogue: f32 partial to C0 (ks=0) or C1 (ks=1); rows guarded.
  float* Cd = ks ? C1 : C0;
#pragma unroll
  for (int m = 0; m < 4; m++)
#pragma unroll
    for (int n = 0; n < 4; n++) {
      int col = col0 + wc * 64 + n * 16 + lr;
#pragma unroll
      for (int r = 0; r < 4; r++) {
        int row = row0 + wr * 64 + m * 16 + lg * 4 + r;
        if (row < NNODES)
          Cd[(size_t)row * FDIM + col] = acc[m][n][r];
      }
    }
}

// ---- k_red: io = (io + p1) * (1/12) + bias  (elementwise, float4) ----
__global__ void k_red(const float* __restrict__ p1, const float* __restrict__ bias,
                      float* __restrict__ io) {
  int e = (blockIdx.x * 256 + threadIdx.x) * 4;   // NNODES*FDIM = 7500*1024
  float4 a = *(const float4*)(io + e);
  float4 b = *(const float4*)(p1 + e);
  float4 bv = *(const float4*)(bias + (e % FDIM));
  const float sc = 1.f / 12.f;
  float4 o;
  o.x = (a.x + b.x) * sc + bv.x;
  o.y = (a.y + b.y) * sc + bv.y;
  o.z = (a.z + b.z) * sc + bv.z;
  o.w = (a.w + b.w) * sc + bv.w;
  *(float4*)(io + e) = o;
}

// ---------------- graph mean pool (batch is sorted) ----------------
__global__ void k_pool(const float* __restrict__ h2, const int* __restrict__ batch,
                       float* __restrict__ g) {
  int gi = blockIdx.x;
  int c = blockIdx.y * 256 + threadIdx.x;
  int lo = 0, hi = NNODES;
  while (lo < hi) { int mid = (lo + hi) >> 1; if (batch[mid] < gi) lo = mid + 1; else hi = mid; }
  int start = lo;
  lo = start; hi = NNODES;
  while (lo < hi) { int mid = (lo + hi) >> 1; if (batch[mid] < gi + 1) lo = mid + 1; else hi = mid; }
  int end = lo;
  int cnt = end - start; if (cnt < 1) cnt = 1;
  float inv = 1.f / (float)cnt;
  float s = 0.f;
  for (int n = start; n < end; n++) s += h2[(size_t)n * FDIM + c];
  g[gi * FDIM + c] = s * inv;
}

// ---------------- MLP head ----------------
__global__ void k_mlp(const float* __restrict__ g, const float* __restrict__ w1,
                      const float* __restrict__ b1, const float* __restrict__ w2,
                      const float* __restrict__ b2, float* __restrict__ out) {
  int gi = blockIdx.x;
  int t = threadIdx.x;  // 128
  __shared__ float gs[FDIM];
  __shared__ float zs[128];
  for (int i = t; i < FDIM; i += 128) gs[i] = g[gi * FDIM + i];
  __syncthreads();
  float a = b1[t];
  for (int k = 0; k < FDIM; k++) a += gs[k] * w1[k * 128 + t];
  zs[t] = (a > 0.f) ? a : 0.f;
  __syncthreads();
  if (t < 4) {
    float o = b2[t];
    for (int i = 0; i < 128; i++) o += zs[i] * w2[i * 4 + t];
    out[gi * 4 + t] = o;
  }
}

extern "C" void kernel_launch(void* const* d_in, const int* in_sizes, int n_in,
                              void* d_out, int out_size, void* d_ws, size_t ws_size,
                              hipStream_t stream) {
  const float* x    = (const float*)d_in[0];
  const int*   ei   = (const int*)d_in[1];
  const int*   batch= (const int*)d_in[2];
  const float* W1   = (const float*)d_in[3];
  const float* as1  = (const float*)d_in[4];
  const float* ad1  = (const float*)d_in[5];
  const float* b1   = (const float*)d_in[6];
  const float* W2   = (const float*)d_in[7];
  const float* as2  = (const float*)d_in[8];
  const float* ad2  = (const float*)d_in[9];
  const float* b2   = (const float*)d_in[10];
  const float* mw1  = (const float*)d_in[11];
  const float* mb1  = (const float*)d_in[12];
  const float* mw2  = (const float*)d_in[13];
  const float* mb2  = (const float*)d_in[14];
  float* out = (float*)d_out;
  (void)in_sizes; (void)n_in; (void)out_size; (void)ws_size;

  char* wsb = (char*)d_ws;
  size_t off = 0;
  auto alloc = [&](size_t bytes) -> void* {
    void* p = wsb + off;
    off += (bytes + 255) & ~(size_t)255;
    return p;
  };
  // ws: y 188.7 + Bt2 14.2 + h1 30.7 + h2 30.7 + small ≈ 265 MB.
  // Split-K partial1 aliases the layer's DEAD h-buffer:
  //   layer 0: hout=h1, cpart=h2 (h2 unused until layer 1, overwritten there)
  //   layer 1: hout=h2, cpart=h1 (h1=xin is dead after k_agg, before k_gemm2)
  u16*  y      = (u16*)alloc((size_t)MPAD * KDIM * 2);     // 188.7 MB (tiled planes)
  u16*  Bt2    = (u16*)alloc((size_t)FDIM * KDIM * 2);     // 14.2 MB (tiled planes)
  float* h1    = (float*)alloc((size_t)NNODES * FDIM * 4); // 30.7 MB
  float* h2    = (float*)alloc((size_t)NNODES * FDIM * 4); // 30.7 MB
  float* sd    = (float*)alloc((size_t)NNODES * 24 * 4);
  float* Ut    = (float*)alloc((size_t)FDIM * 24 * 4);
  int*  counts = (int*)alloc((size_t)NNODES * 4);
  int*  offs   = (int*)alloc((size_t)(NNODES + 1) * 4);
  int*  cursor = (int*)alloc((size_t)NNODES * 4);
  int*  elist  = (int*)alloc((size_t)ETOT * 4);
  float* gbuf  = (float*)alloc((size_t)NGRAPH * FDIM * 4);

  // CSR by dst (edges identical for both layers)
  hipMemsetAsync(counts, 0, NNODES * 4, stream);
  k_zpad<<<(NPLANE * (MPAD - NNODES) * 8 + 255) / 256, 256, 0, stream>>>(y);
  k_count<<<(ETOT + 255) / 256, 256, 0, stream>>>(ei + NEDGES, counts);
  k_scan<<<1, 256, 0, stream>>>(counts, offs);
  k_seed<<<(NNODES + 255) / 256, 256, 0, stream>>>(offs, cursor);
  k_scatter<<<(ETOT + 255) / 256, 256, 0, stream>>>(ei + NEDGES, cursor, elist);

  for (int layer = 0; layer < 2; layer++) {
    const float* xin  = layer ? h1  : x;
    const float* W    = layer ? W2  : W1;
    const float* asrc = layer ? as2 : as1;
    const float* adst = layer ? ad2 : ad1;
    const float* bb   = layer ? b2  : b1;
    float* hout       = layer ? h2  : h1;
    float* cpart      = layer ? h1  : h2;   // dead buffer this layer (see alloc note)

    k_U<<<FDIM, 256, 0, stream>>>(W, asrc, adst, Ut);
    k_sd<<<(NNODES + 19) / 20, 256, 0, stream>>>(xin, Ut, sd);
    k_trans2<<<dim3(FDIM / 32, KDIM / 32), dim3(32, 8), 0, stream>>>(W, Bt2);
    k_agg<<<(NNODES + 3) / 4, 256, 0, stream>>>(xin, ei, offs, elist, sd, y);
    k_gemm2<<<480, 512, 0, stream>>>(y, Bt2, hout, cpart);
    k_red<<<NNODES * FDIM / 1024, 256, 0, stream>>>(cpart, bb, hout);
  }

  k_pool<<<dim3(NGRAPH, 3), 256, 0, stream>>>(h2, batch, gbuf);
  k_mlp<<<NGRAPH, 128, 0, stream>>>(gbuf, mw1, mb1, mw2, mb2, out);
}

// Round 11
// 793.294 us; speedup vs baseline: 1.1359x; 1.1359x over previous
//
#include <hip/hip_runtime.h>
#include <stdint.h>

typedef unsigned short u16;
typedef unsigned int   u32;

#define NNODES 10000
#define NEDGES 20000
#define ETOT   30000
#define NHEADS 12
#define CDIM   768
#define FDIM   768
#define KDIM   9216    // h*768+k flattened head-input dim (GEMM K)
#define NGRAPH 64
#define MPAD   10240   // y padded rows; pad rows zeroed per plane, outputs guarded
#define NEG_SLOPE 0.2f
#define DMAX   32      // max in-degree incl. self-loop; max of 10000 Poisson(2) ~ 14
#define NPLANE 144     // KDIM/64 K-planes in the tiled y/Bt2 layouts

typedef __attribute__((ext_vector_type(8))) short short8;
typedef __attribute__((ext_vector_type(4))) float f32x4;

__device__ __forceinline__ u16 f32_bf16(float f) {
  u32 u = __float_as_uint(f);
  u = (u + 0x7FFFu + ((u >> 16) & 1u)) >> 16;
  return (u16)u;
}
__device__ __forceinline__ float bf16_f32(u16 v) {
  return __uint_as_float(((u32)v) << 16);
}

// ---------------- CSR build ----------------
__global__ void k_count(const int* __restrict__ dste, int* __restrict__ counts) {
  int e = blockIdx.x * blockDim.x + threadIdx.x;
  if (e >= ETOT) return;
  int dst;
  if (e < NEDGES) dst = dste[e]; else dst = e - NEDGES;
  atomicAdd(&counts[dst], 1);
}

__global__ void k_scan(const int* __restrict__ counts, int* __restrict__ offs) {
  __shared__ int part[256];
  int t = threadIdx.x;
  const int chunk = 40;
  int beg = t * chunk;
  int end = beg + chunk; if (end > NNODES) end = NNODES;
  int s = 0;
  for (int i = beg; i < end && i < NNODES; i++) s += counts[i];
  part[t] = s;
  __syncthreads();
  for (int d = 1; d < 256; d <<= 1) {
    int v = (t >= d) ? part[t - d] : 0;
    __syncthreads();
    part[t] += v;
    __syncthreads();
  }
  int base = (t == 0) ? 0 : part[t - 1];
  for (int i = beg; i < end && i < NNODES; i++) { offs[i] = base; base += counts[i]; }
  if (t == 255) offs[NNODES] = base;
}

__global__ void k_seed(const int* __restrict__ offs, int* __restrict__ cursor) {
  int n = blockIdx.x * blockDim.x + threadIdx.x;
  if (n < NNODES) cursor[n] = offs[n];
}

__global__ void k_scatter(const int* __restrict__ dste, int* __restrict__ cursor,
                          int* __restrict__ elist) {
  int e = blockIdx.x * blockDim.x + threadIdx.x;
  if (e >= ETOT) return;
  int dst;
  if (e < NEDGES) dst = dste[e]; else dst = e - NEDGES;
  int pos = atomicAdd(&cursor[dst], 1);
  elist[pos] = e;
}

// ------- Ut[o*768+k] = sum_c W[k, h*768+c] * a[h, c] ; 4 waves x 6 o's per block -------
__global__ void k_U(const float* __restrict__ W, const float* __restrict__ a_src,
                    const float* __restrict__ a_dst, float* __restrict__ Ut) {
  int k = blockIdx.x;
  int t = threadIdx.x, w = t >> 6, l = t & 63;
  const float* Wrow = W + (size_t)k * KDIM;
#pragma unroll
  for (int q = 0; q < 6; q++) {
    int o = w * 6 + q;
    int h = (o < 12) ? o : o - 12;
    const float* av = (o < 12) ? (a_src + h * CDIM) : (a_dst + h * CDIM);
    const float* wr = Wrow + h * CDIM;
    float p = 0.f;
    for (int c = l; c < CDIM; c += 64) p += wr[c] * av[c];
#pragma unroll
    for (int d = 32; d > 0; d >>= 1) p += __shfl_down(p, d, 64);
    if (l == 0) Ut[o * FDIM + k] = p;
  }
}

// ---- sd: Ut staged in LDS once per block; 20 nodes/block. ----
__global__ void k_sd(const float* __restrict__ xin, const float* __restrict__ Ut,
                     float* __restrict__ sd) {
  __shared__ float UtS[24 * FDIM];   // 73728 B
  int t = threadIdx.x, w = t >> 6, l = t & 63;
  const float4* U4 = (const float4*)Ut;
  float4* S4 = (float4*)UtS;
  for (int i = t; i < 24 * FDIM / 4; i += 256) S4[i] = U4[i];
  __syncthreads();
#pragma unroll
  for (int rep = 0; rep < 5; rep++) {
    int n = blockIdx.x * 20 + w * 5 + rep;
    if (n >= NNODES) continue;
    const float* xr = xin + (size_t)n * FDIM;
    float4 x0 = *(const float4*)(xr + 4 * l);
    float4 x1 = *(const float4*)(xr + 4 * l + 256);
    float4 x2 = *(const float4*)(xr + 4 * l + 512);
#pragma unroll
    for (int o = 0; o < 24; o++) {
      const float4* up = (const float4*)(UtS + o * FDIM + 4 * l);
      float4 u0 = up[0];
      float4 u1 = up[64];
      float4 u2 = up[128];
      float a = x0.x * u0.x + x0.y * u0.y + x0.z * u0.z + x0.w * u0.w
              + x1.x * u1.x + x1.y * u1.y + x1.z * u1.z + x1.w * u1.w
              + x2.x * u2.x + x2.y * u2.y + x2.z * u2.z + x2.w * u2.w;
#pragma unroll
      for (int d = 32; d > 0; d >>= 1) a += __shfl_xor(a, d, 64);
      if (l == 0) sd[n * 24 + o] = a;
    }
  }
}

// -------- Bt2 K-TILED: Bt2[kt][c][64] = bf16(W[k, h*768+c]), kt = (h*768+k)/64.
//          Dense 64B-contiguous rows so GEMM staging loads are unscattered. --------
__global__ void k_trans2(const float* __restrict__ W, u16* __restrict__ Bt2) {
  int kb = blockIdx.x * 32, jt = blockIdx.y * 32;   // kb: W-row tile; jt = h*768+c tile
  int tx = threadIdx.x, ty = threadIdx.y;  // 32, 8
  __shared__ float tile[32][33];
  int h0 = jt / 768, c0 = jt - h0 * 768;
  int plane = (h0 * 768 + kb) >> 6;        // kb%64 in {0,32}: tx<32 never carries
#pragma unroll
  for (int r = 0; r < 4; r++)
    tile[ty + 8 * r][tx] = W[(size_t)(kb + ty + 8 * r) * KDIM + jt + tx];
  __syncthreads();
#pragma unroll
  for (int r = 0; r < 4; r++)
    Bt2[(size_t)plane * (768 * 64) + (size_t)(c0 + ty + 8 * r) * 64 + ((kb + tx) & 63)]
        = f32_bf16(tile[tx][ty + 8 * r]);
}

// ---- k_zpad: zero pad rows [NNODES,MPAD) of every y plane (run once; k_agg
//      only writes n<NNODES so pads stay zero across layers). ----
__global__ void k_zpad(u16* __restrict__ y) {
  int idx = blockIdx.x * 256 + threadIdx.x;   // 144 planes * 240 rows * 64 / 8 = 276480
  if (idx >= NPLANE * (MPAD - NNODES) * 8) return;
  int e = idx * 8;
  int plane = e / ((MPAD - NNODES) * 64);
  int rem = e - plane * ((MPAD - NNODES) * 64);
  u16* p = y + (size_t)plane * (MPAD * 64) + (size_t)NNODES * 64 + rem;
  *(short8*)p = (short8){0, 0, 0, 0, 0, 0, 0, 0};
}

// ---- k_agg: softmax + aggregation in input space (r7: ~86 us/layer faster than
//      Hbig-gather). Output K-TILED: y[kt][n][64], kt = (h*768+pass*256+4l)/64. ----
__global__ void k_agg(const float* __restrict__ xin, const int* __restrict__ ei,
                      const int* __restrict__ offs, const int* __restrict__ elist,
                      const float* __restrict__ sd, u16* __restrict__ y) {
  int t = threadIdx.x, w = t >> 6, l = t & 63;
  int n = blockIdx.x * 4 + w;
  __shared__ int   srcsS[4][DMAX];
  __shared__ float alphS[4][NHEADS * DMAX];
  if (n >= NNODES) return;          // no block barriers below
  int* srcs = srcsS[w];
  float* alph = alphS[w];
  int beg = offs[n];
  int deg = offs[n + 1] - beg;
  if (deg > DMAX) deg = DMAX;
  if (l < deg) {
    int e = elist[beg + l];
    srcs[l] = (e < NEDGES) ? ei[e] : e - NEDGES;
  }
  __builtin_amdgcn_wave_barrier();
  for (int p = l; p < deg * NHEADS; p += 64) {
    int i = p / NHEADS, h = p - i * NHEADS;
    float v = sd[srcs[i] * 24 + h] + sd[n * 24 + 12 + h];
    v = (v > 0.f) ? v : NEG_SLOPE * v;
    alph[h * DMAX + i] = v;
  }
  __builtin_amdgcn_wave_barrier();
  if (l < NHEADS) {
    float m = -1e30f;
    for (int i = 0; i < deg; i++) m = fmaxf(m, alph[l * DMAX + i]);
    float s = 0.f;
    for (int i = 0; i < deg; i++) {
      float ex = expf(alph[l * DMAX + i] - m);
      alph[l * DMAX + i] = ex;
      s += ex;
    }
    float inv = 1.f / (s + 1e-16f);
    for (int i = 0; i < deg; i++) alph[l * DMAX + i] *= inv;
  }
  __builtin_amdgcn_wave_barrier();
  int lg = l >> 4, lo16 = l & 15;
#pragma unroll
  for (int pass = 0; pass < 3; pass++) {
    float4 acc12[NHEADS];
#pragma unroll
    for (int h = 0; h < NHEADS; h++) acc12[h] = make_float4(0.f, 0.f, 0.f, 0.f);
    for (int i = 0; i < deg; i++) {
      float4 xs = *(const float4*)(xin + (size_t)srcs[i] * FDIM + pass * 256 + 4 * l);
#pragma unroll
      for (int h = 0; h < NHEADS; h++) {
        float a = alph[h * DMAX + i];
        acc12[h].x += a * xs.x;
        acc12[h].y += a * xs.y;
        acc12[h].z += a * xs.z;
        acc12[h].w += a * xs.w;
      }
    }
#pragma unroll
    for (int h = 0; h < NHEADS; h++) {
      ushort4 pv;
      pv.x = f32_bf16(acc12[h].x);
      pv.y = f32_bf16(acc12[h].y);
      pv.z = f32_bf16(acc12[h].z);
      pv.w = f32_bf16(acc12[h].w);
      int plane = h * 12 + pass * 4 + lg;       // (h*768+pass*256+4l)/64
      *(ushort4*)(y + (size_t)plane * (MPAD * 64) + (size_t)n * 64 + 4 * lo16) = pv;
    }
  }
}

// ============================================================================
// GEMM2 — m97-PROVEN SIMPLE STRUCTURE, scaled: partial[n,c] = sum y*Bt2, splitK=2.
// r9 POST-MORTEM: occupancy fix engaged (36%) but (a) the 64B-row swizzle
// left 4-way bank conflicts (1.77e7) and (b) 64x64 wave tiles sit AT the
// LDS-read roofline (32 FLOP/B) -> LDS reads became the critical path and
// MfmaUtil stayed 27%. This version:
//   - tile 256x128, BK=64, 4 waves of 128x64 (42.7 FLOP/LDS-byte, MFMA-side)
//   - SINGLE-buffered 48 KiB LDS, plain 2-phase loop {stage; sync; compute;
//     sync} — the m97/m103 recipe (874-912 TF). The vmcnt drain at the
//     barrier is hidden by the OTHER resident block (m114 cross-block
//     overlap) — that was m97's actual mechanism at 3 blocks/CU.
//   - r6-PROVEN swizzle: 128B rows, read XOR (lr&7)<<4, source pre-swizzle
//     (cc^(rb&7)) — measured 0 conflicts at this exact geometry.
//   - 2 blocks/CU: LDS 48K (fits 3), VGPR ~195 (acc 128 + frags 48) < 256.
//   - grid 40 rows x 6 cols x 2 splits = 480 ~ 1.9 blocks/CU, single round;
//     cx fastest -> 6 consecutive blocks share one A panel in L2.
// LDS floor: 3.3 GB reads @ 69 TB/s + 1.66 GB writes ~ 72 us; MFMA floor 60.
// ============================================================================
#define GLL16(G, L) __builtin_amdgcn_global_load_lds( \
  (const __attribute__((address_space(1))) void*)(G), \
  (__attribute__((address_space(3))) void*)(L), 16, 0, 0)

__global__ __launch_bounds__(256, 2) void k_gemm2(const u16* __restrict__ A,
    const u16* __restrict__ B, float* __restrict__ C0, float* __restrict__ C1) {
  __shared__ __align__(16) u16 As[256 * 64];   // 32 KB
  __shared__ __align__(16) u16 Bs[128 * 64];   // 16 KB; total 48 KiB
  int t = threadIdx.x;
  int w = t >> 6, l = t & 63;
  int bid = blockIdx.x;                 // 480
  int xcd = bid & 7, j = bid >> 3;      // [0,60)
  int p = j / 12, rem = j - p * 12;
  int ks = rem / 6, cx = rem - ks * 6;  // cx fastest: 6 blocks share A panel
  int row0 = (xcd * 5 + p) * 256, col0 = cx * 128;
  int K0b = ks * (NPLANE / 2);          // plane base: ks*72
  int wr = w >> 1, wc = w & 1;          // wave grid 2M x 2N, wave tile 128x64
  int lr = l & 15, lg = l >> 4;
  int swzr = (lr & 7) << 4;             // r6-proven read XOR (row&7 == lr&7)

  f32x4 acc[8][4] = {};

  auto stage = [&](int pl) {
    // A: 256 rows x 128B = 2048 chunks, 8 issues; B: 128 rows, 4 issues.
#pragma unroll
    for (int i = 0; i < 8; i++) {
      int idx = i * 256 + t;
      int rb = idx >> 3, cc = idx & 7;
      const u16* g = A + (size_t)pl * (MPAD * 64)
                       + (size_t)(row0 + rb) * 64 + ((cc ^ (rb & 7)) * 8);
      GLL16(g, (u16*)As + idx * 8);
    }
#pragma unroll
    for (int i = 0; i < 4; i++) {
      int idx = i * 256 + t;
      int rb = idx >> 3, cc = idx & 7;
      const u16* g = B + (size_t)pl * (768 * 64)
                       + (size_t)(col0 + rb) * 64 + ((cc ^ (rb & 7)) * 8);
      GLL16(g, (u16*)Bs + idx * 8);
    }
  };

  const int NIT = NPLANE / 2;   // 72 K-tiles of 64
  for (int s = 0; s < NIT; s++) {
    stage(K0b + s);
    __syncthreads();              // drains vmcnt; other block computes meanwhile
    short8 a[8], b[4];
#pragma unroll
    for (int kc = 0; kc < 2; kc++) {
      int koff = (kc * 64 + lg * 16);
#pragma unroll
      for (int m = 0; m < 8; m++) {
        int row = wr * 128 + m * 16 + lr;
        a[m] = *(const short8*)((const char*)As + row * 128 + (koff ^ swzr));
      }
#pragma unroll
      for (int n = 0; n < 4; n++) {
        int row = wc * 64 + n * 16 + lr;
        b[n] = *(const short8*)((const char*)Bs + row * 128 + (koff ^ swzr));
      }
      __builtin_amdgcn_s_setprio(1);
#pragma unroll
      for (int m = 0; m < 8; m++)
#pragma unroll
        for (int n = 0; n < 4; n++)
          acc[m][n] = __builtin_amdgcn_mfma_f32_16x16x32_bf16(
              a[m], b[n], acc[m][n], 0, 0, 0);
      __builtin_amdgcn_s_setprio(0);
    }
    __syncthreads();              // compute done before next stage overwrites
  }

  // epilogue: f32 partial to C0 (ks=0) or C1 (ks=1); rows guarded.
  float* Cd = ks ? C1 : C0;
#pragma unroll
  for (int m = 0; m < 8; m++)
#pragma unroll
    for (int n = 0; n < 4; n++) {
      int col = col0 + wc * 64 + n * 16 + lr;
#pragma unroll
      for (int r = 0; r < 4; r++) {
        int row = row0 + wr * 128 + m * 16 + lg * 4 + r;
        if (row < NNODES)
          Cd[(size_t)row * FDIM + col] = acc[m][n][r];
      }
    }
}

// ---- k_red: io = (io + p1) * (1/12) + bias  (elementwise, float4) ----
__global__ void k_red(const float* __restrict__ p1, const float* __restrict__ bias,
                      float* __restrict__ io) {
  int e = (blockIdx.x * 256 + threadIdx.x) * 4;   // NNODES*FDIM = 7500*1024
  float4 a = *(const float4*)(io + e);
  float4 b = *(const float4*)(p1 + e);
  float4 bv = *(const float4*)(bias + (e % FDIM));
  const float sc = 1.f / 12.f;
  float4 o;
  o.x = (a.x + b.x) * sc + bv.x;
  o.y = (a.y + b.y) * sc + bv.y;
  o.z = (a.z + b.z) * sc + bv.z;
  o.w = (a.w + b.w) * sc + bv.w;
  *(float4*)(io + e) = o;
}

// ---------------- graph mean pool (batch is sorted) ----------------
__global__ void k_pool(const float* __restrict__ h2, const int* __restrict__ batch,
                       float* __restrict__ g) {
  int gi = blockIdx.x;
  int c = blockIdx.y * 256 + threadIdx.x;
  int lo = 0, hi = NNODES;
  while (lo < hi) { int mid = (lo + hi) >> 1; if (batch[mid] < gi) lo = mid + 1; else hi = mid; }
  int start = lo;
  lo = start; hi = NNODES;
  while (lo < hi) { int mid = (lo + hi) >> 1; if (batch[mid] < gi + 1) lo = mid + 1; else hi = mid; }
  int end = lo;
  int cnt = end - start; if (cnt < 1) cnt = 1;
  float inv = 1.f / (float)cnt;
  float s = 0.f;
  for (int n = start; n < end; n++) s += h2[(size_t)n * FDIM + c];
  g[gi * FDIM + c] = s * inv;
}

// ---------------- MLP head ----------------
__global__ void k_mlp(const float* __restrict__ g, const float* __restrict__ w1,
                      const float* __restrict__ b1, const float* __restrict__ w2,
                      const float* __restrict__ b2, float* __restrict__ out) {
  int gi = blockIdx.x;
  int t = threadIdx.x;  // 128
  __shared__ float gs[FDIM];
  __shared__ float zs[128];
  for (int i = t; i < FDIM; i += 128) gs[i] = g[gi * FDIM + i];
  __syncthreads();
  float a = b1[t];
  for (int k = 0; k < FDIM; k++) a += gs[k] * w1[k * 128 + t];
  zs[t] = (a > 0.f) ? a : 0.f;
  __syncthreads();
  if (t < 4) {
    float o = b2[t];
    for (int i = 0; i < 128; i++) o += zs[i] * w2[i * 4 + t];
    out[gi * 4 + t] = o;
  }
}

extern "C" void kernel_launch(void* const* d_in, const int* in_sizes, int n_in,
                              void* d_out, int out_size, void* d_ws, size_t ws_size,
                              hipStream_t stream) {
  const float* x    = (const float*)d_in[0];
  const int*   ei   = (const int*)d_in[1];
  const int*   batch= (const int*)d_in[2];
  const float* W1   = (const float*)d_in[3];
  const float* as1  = (const float*)d_in[4];
  const float* ad1  = (const float*)d_in[5];
  const float* b1   = (const float*)d_in[6];
  const float* W2   = (const float*)d_in[7];
  const float* as2  = (const float*)d_in[8];
  const float* ad2  = (const float*)d_in[9];
  const float* b2   = (const float*)d_in[10];
  const float* mw1  = (const float*)d_in[11];
  const float* mb1  = (const float*)d_in[12];
  const float* mw2  = (const float*)d_in[13];
  const float* mb2  = (const float*)d_in[14];
  float* out = (float*)d_out;
  (void)in_sizes; (void)n_in; (void)out_size; (void)ws_size;

  char* wsb = (char*)d_ws;
  size_t off = 0;
  auto alloc = [&](size_t bytes) -> void* {
    void* p = wsb + off;
    off += (bytes + 255) & ~(size_t)255;
    return p;
  };
  // ws: y 188.7 + Bt2 14.2 + h1 30.7 + h2 30.7 + small ≈ 265 MB.
  // Split-K partial1 aliases the layer's DEAD h-buffer:
  //   layer 0: hout=h1, cpart=h2 (h2 unused until layer 1, overwritten there)
  //   layer 1: hout=h2, cpart=h1 (h1=xin is dead after k_agg, before k_gemm2)
  u16*  y      = (u16*)alloc((size_t)MPAD * KDIM * 2);     // 188.7 MB (tiled planes)
  u16*  Bt2    = (u16*)alloc((size_t)FDIM * KDIM * 2);     // 14.2 MB (tiled planes)
  float* h1    = (float*)alloc((size_t)NNODES * FDIM * 4); // 30.7 MB
  float* h2    = (float*)alloc((size_t)NNODES * FDIM * 4); // 30.7 MB
  float* sd    = (float*)alloc((size_t)NNODES * 24 * 4);
  float* Ut    = (float*)alloc((size_t)FDIM * 24 * 4);
  int*  counts = (int*)alloc((size_t)NNODES * 4);
  int*  offs   = (int*)alloc((size_t)(NNODES + 1) * 4);
  int*  cursor = (int*)alloc((size_t)NNODES * 4);
  int*  elist  = (int*)alloc((size_t)ETOT * 4);
  float* gbuf  = (float*)alloc((size_t)NGRAPH * FDIM * 4);

  // CSR by dst (edges identical for both layers)
  hipMemsetAsync(counts, 0, NNODES * 4, stream);
  k_zpad<<<(NPLANE * (MPAD - NNODES) * 8 + 255) / 256, 256, 0, stream>>>(y);
  k_count<<<(ETOT + 255) / 256, 256, 0, stream>>>(ei + NEDGES, counts);
  k_scan<<<1, 256, 0, stream>>>(counts, offs);
  k_seed<<<(NNODES + 255) / 256, 256, 0, stream>>>(offs, cursor);
  k_scatter<<<(ETOT + 255) / 256, 256, 0, stream>>>(ei + NEDGES, cursor, elist);

  for (int layer = 0; layer < 2; layer++) {
    const float* xin  = layer ? h1  : x;
    const float* W    = layer ? W2  : W1;
    const float* asrc = layer ? as2 : as1;
    const float* adst = layer ? ad2 : ad1;
    const float* bb   = layer ? b2  : b1;
    float* hout       = layer ? h2  : h1;
    float* cpart      = layer ? h1  : h2;   // dead buffer this layer (see alloc note)

    k_U<<<FDIM, 256, 0, stream>>>(W, asrc, adst, Ut);
    k_sd<<<(NNODES + 19) / 20, 256, 0, stream>>>(xin, Ut, sd);
    k_trans2<<<dim3(FDIM / 32, KDIM / 32), dim3(32, 8), 0, stream>>>(W, Bt2);
    k_agg<<<(NNODES + 3) / 4, 256, 0, stream>>>(xin, ei, offs, elist, sd, y);
    k_gemm2<<<480, 256, 0, stream>>>(y, Bt2, hout, cpart);
    k_red<<<NNODES * FDIM / 1024, 256, 0, stream>>>(cpart, bb, hout);
  }

  k_pool<<<dim3(NGRAPH, 3), 256, 0, stream>>>(h2, batch, gbuf);
  k_mlp<<<NGRAPH, 128, 0, stream>>>(gbuf, mw1, mb1, mw2, mb2, out);
}